// Round 11
// baseline (3404.686 us; speedup 1.0000x reference)
//
#include <hip/hip_runtime.h>

#define BB 16
#define NN 2048
#define NITERS 100

// k = log2(e)/eps, eps = 0.05
#define K2E      28.853900817779268f
#define TWO_K2E  57.707801635558536f
#define INV2K    0.017328679513998632f   // 1/(2k)
#define INV_K2E  0.034657359027997264f
#define INV4K    0.008664339756999316f   // 1/(4k)
#define LMU      (-11.0f)                // log2(1/2048)

#if __has_builtin(__builtin_amdgcn_exp2f)
#define EXP2F(x) __builtin_amdgcn_exp2f(x)
#else
#define EXP2F(x) exp2f(x)
#endif

typedef float v2f __attribute__((ext_vector_type(2)));

// device-coherent (LLC-homed, sc1) accessors for the dual arrays
#define DSTORE(p, v) __hip_atomic_store((p), (v), __ATOMIC_RELAXED, __HIP_MEMORY_SCOPE_AGENT)
#define DLOAD(p)     __hip_atomic_load((p), __ATOMIC_RELAXED, __HIP_MEMORY_SCOPE_AGENT)

// Sum-pass (R8/R10-verified): 8 rows/wave (coords from LDS, raw = u*INV2K),
// own j-half of SoA tables t0..t2 + dual td. Packed-f32 d-computation.
// Returns combined row-sum on lanes 0..7 (row = rr involution).
__device__ __forceinline__ float sumpass(
    const float* __restrict__ u0, const float* __restrict__ u1,
    const float* __restrict__ u2,
    const float* __restrict__ t0, const float* __restrict__ t1,
    const float* __restrict__ t2, const float* __restrict__ td,
    int rloc, int jh, int lane, int w, float* pcomb)
{
    v2f xp0[4], xp1[4], xp2[4], acc2[4];
    #pragma unroll
    for (int p = 0; p < 4; ++p) {
        xp0[p] = (v2f){u0[rloc + 2*p] * INV2K, u0[rloc + 2*p + 1] * INV2K};
        xp1[p] = (v2f){u1[rloc + 2*p] * INV2K, u1[rloc + 2*p + 1] * INV2K};
        xp2[p] = (v2f){u2[rloc + 2*p] * INV2K, u2[rloc + 2*p + 1] * INV2K};
        acc2[p] = (v2f){0.f, 0.f};
    }
    const int jb = (jh << 10) + lane;
    #pragma unroll 2
    for (int s = 0; s < 16; ++s) {
        const int p = jb + (s << 6);
        const float a0 = t0[p], a1 = t1[p], a2 = t2[p], ad = td[p];
        const v2f a0v = (v2f){a0, a0}, a1v = (v2f){a1, a1};
        const v2f a2v = (v2f){a2, a2}, adv = (v2f){ad, ad};
        #pragma unroll
        for (int q = 0; q < 4; ++q) {
            v2f d = __builtin_elementwise_fma(xp0[q], a0v,
                    __builtin_elementwise_fma(xp1[q], a1v,
                    __builtin_elementwise_fma(xp2[q], a2v, adv)));
            acc2[q] += (v2f){EXP2F(d.x), EXP2F(d.y)};
        }
    }
    float acc[8];
    #pragma unroll
    for (int p = 0; p < 4; ++p) { acc[2*p] = acc2[p].x; acc[2*p+1] = acc2[p].y; }
    // multi-value butterfly (verified R3/R5/R8); lanes<8 end with row rr
    const bool b0 = lane & 1, b1 = lane & 2, b2 = lane & 4;
    float v4[4], v2_[2], v1;
    #pragma unroll
    for (int i = 0; i < 4; ++i) {
        float recv = __shfl_xor(b0 ? acc[i] : acc[i+4], 1, 64);
        v4[i] = (b0 ? acc[i+4] : acc[i]) + recv;
    }
    #pragma unroll
    for (int i = 0; i < 2; ++i) {
        float recv = __shfl_xor(b1 ? v4[i] : v4[i+2], 2, 64);
        v2_[i] = (b1 ? v4[i+2] : v4[i]) + recv;
    }
    {
        float recv = __shfl_xor(b2 ? v2_[0] : v2_[1], 4, 64);
        v1 = (b2 ? v2_[1] : v2_[0]) + recv;
    }
    v1 += __shfl_xor(v1, 8, 64);
    v1 += __shfl_xor(v1, 16, 64);
    v1 += __shfl_xor(v1, 32, 64);
    const int rr = ((lane & 1) << 2) | (lane & 2) | ((lane >> 2) & 1);
    if (lane < 8) pcomb[w * 8 + rr] = v1;
    __syncthreads();
    float S = 0.f;
    if (lane < 8) S = v1 + pcomb[(w ^ 1) * 8 + rr];
    return S;
}

// Epilogue partial (R8-verified): sum_j P_ij*C_ij, 8 rows x own j-half.
__device__ __forceinline__ float epil(
    const float* __restrict__ u0, const float* __restrict__ u1,
    const float* __restrict__ u2,
    const float* __restrict__ t0, const float* __restrict__ t1,
    const float* __restrict__ t2, const float* __restrict__ td,
    const float* __restrict__ sA, int rloc, int jh, int lane)
{
    float xr0[8], xr1[8], xr2[8], Ak[8], x2k[8];
    #pragma unroll
    for (int k = 0; k < 8; ++k) {
        xr0[k] = u0[rloc + k] * INV2K;
        xr1[k] = u1[rloc + k] * INV2K;
        xr2[k] = u2[rloc + k] * INV2K;
        Ak[k]  = sA[rloc + k];
        x2k[k] = K2E * (xr0[k]*xr0[k] + xr1[k]*xr1[k] + xr2[k]*xr2[k]);
    }
    float acc = 0.f;
    const int jb = (jh << 10) + lane;
    for (int s = 0; s < 16; ++s) {
        const int p = jb + (s << 6);
        const float a0 = t0[p], a1 = t1[p], a2 = t2[p], tb = td[p];
        const float q2 = (a0*a0 + a1*a1 + a2*a2) * INV4K;   // k|y|^2
        #pragma unroll
        for (int k = 0; k < 8; ++k) {
            float d = fmaf(xr0[k], a0, fmaf(xr1[k], a1, fmaf(xr2[k], a2, tb)));
            float P = EXP2F(d + Ak[k]);                       // exp(logP)
            float C = fmaxf((x2k[k] + q2 - (d - tb)) * INV_K2E, 0.f);
            acc = fmaf(P, C, acc);
        }
    }
    return acc;
}

// grid: 256 blocks x 1024 threads (1 block/CU). pair = blk&7. Deterministic
// software pipeline (R8-verified): every wait has one full compute phase
// between the matching posts and the wait. Dual arrays are LLC-homed
// (agent-scope sc1 accesses) -> no threadfence/L2-writeback in the barrier:
// the compiler-emitted vmcnt(0)-before-s_barrier drains all sc1 stores to
// the device coherence point before tid0 posts.
__global__ __launch_bounds__(1024) void emd_sinkhorn(
    const float* __restrict__ x, const float* __restrict__ y,
    float* __restrict__ Af, float* __restrict__ Bf,
    int* __restrict__ cntb, float* __restrict__ out)
{
    extern __shared__ float S[];     // 16*NN floats = 128 KB
    __shared__ float pcomb[16 * 8];
    __shared__ float wsum[16];

    const int tid  = threadIdx.x;
    const int lane = tid & 63;
    const int w    = tid >> 6;        // 0..15
    const int pr   = w >> 1;          // wave-pair 0..7
    const int jh   = w & 1;           // j-half
    const int blk  = blockIdx.x;
    const int pair = blk & 7;         // = XCD id under round-robin (perf only)
    const int q    = blk >> 3;        // 0..31: row-slice within pair
    const int b0   = pair * 2, b1 = b0 + 1;
    const int base0 = b0 * NN, base1 = b1 * NN;
    const int rloc  = q * 64 + pr * 8;      // within-batch row base
    int* c0 = cntb + b0 * 64;
    int* c1 = cntb + b1 * 64;

    // LDS carve: per batch 8 slots of NN floats (SoA — conflict-free)
    float *sy00 = S,            *sy10 = S +  1*NN, *sy20 = S +  2*NN;
    float *sx00 = S +  3*NN,    *sx10 = S +  4*NN, *sx20 = S +  5*NN;
    float *sA0  = S +  6*NN,    *sB0  = S +  7*NN;
    float *sy01 = S +  8*NN,    *sy11 = S +  9*NN, *sy21 = S + 10*NN;
    float *sx01 = S + 11*NN,    *sx11 = S + 12*NN, *sx21 = S + 13*NN;
    float *sA1  = S + 14*NN,    *sB1  = S + 15*NN;

    // ---- prologue: stage 2k-scaled tables; B0 = -k|y|^2 ----
    #pragma unroll
    for (int v = 0; v < 2; ++v) {
        const int p = tid + (v << 10);
        {
            const float* px = x + 3 * (size_t)(base0 + p);
            sx00[p] = TWO_K2E * px[0]; sx10[p] = TWO_K2E * px[1]; sx20[p] = TWO_K2E * px[2];
            const float* py = y + 3 * (size_t)(base0 + p);
            const float a = py[0], b = py[1], c = py[2];
            sy00[p] = TWO_K2E * a; sy10[p] = TWO_K2E * b; sy20[p] = TWO_K2E * c;
            sB0[p]  = -K2E * (a*a + b*b + c*c);
        }
        {
            const float* px = x + 3 * (size_t)(base1 + p);
            sx01[p] = TWO_K2E * px[0]; sx11[p] = TWO_K2E * px[1]; sx21[p] = TWO_K2E * px[2];
            const float* py = y + 3 * (size_t)(base1 + p);
            const float a = py[0], b = py[1], c = py[2];
            sy01[p] = TWO_K2E * a; sy11[p] = TWO_K2E * b; sy21[p] = TWO_K2E * c;
            sB1[p]  = -K2E * (a*a + b*b + c*c);
        }
    }
    __syncthreads();

    const int rr = ((lane & 1) << 2) | (lane & 2) | ((lane >> 2) & 1);

    // fused post+wait: one tid0 critical section between two block syncs.
    // No threadfence: sc1 dual stores drained by the barrier's vmcnt(0);
    // release/acquire on the counter ops give the ordering.
    #define PW(cpost, cwait, tgt) do { __syncthreads();                         \
        if (tid == 0) {                                                         \
            __hip_atomic_fetch_add((cpost), 1, __ATOMIC_RELEASE,                \
                                   __HIP_MEMORY_SCOPE_AGENT);                   \
            while (__hip_atomic_load((cwait), __ATOMIC_RELAXED,                 \
                                     __HIP_MEMORY_SCOPE_AGENT) < (tgt))         \
                __builtin_amdgcn_s_sleep(1);                                    \
            (void)__hip_atomic_load((cwait), __ATOMIC_ACQUIRE,                  \
                                    __HIP_MEMORY_SCOPE_AGENT);                  \
        }                                                                       \
        __syncthreads(); } while (0)

    #define PONLY(cpost) do { __syncthreads();                                  \
        if (tid == 0)                                                           \
            __hip_atomic_fetch_add((cpost), 1, __ATOMIC_RELEASE,                \
                                   __HIP_MEMORY_SCOPE_AGENT);                   \
        __syncthreads(); } while (0)

    #define WONLY(cwait, tgt) do { __syncthreads();                             \
        if (tid == 0) {                                                         \
            while (__hip_atomic_load((cwait), __ATOMIC_RELAXED,                 \
                                     __HIP_MEMORY_SCOPE_AGENT) < (tgt))         \
                __builtin_amdgcn_s_sleep(1);                                    \
            (void)__hip_atomic_load((cwait), __ATOMIC_ACQUIRE,                  \
                                    __HIP_MEMORY_SCOPE_AGENT);                  \
        }                                                                       \
        __syncthreads(); } while (0)

    // stage 2048 duals from LLC into LDS (2 sc1 loads/thread)
    #define STAGE(dst, src) do {                                                \
        (dst)[2*tid]     = DLOAD((src) + 2*tid);                                \
        (dst)[2*tid + 1] = DLOAD((src) + 2*tid + 1);                            \
        __syncthreads(); } while (0)

    for (int it = 0; it < NITERS; ++it) {
        // ---- fA0 ----
        {
            float Sc = sumpass(sx00, sx10, sx20, sy00, sy10, sy20, sB0,
                               rloc, jh, lane, w, pcomb);
            if (lane < 8 && jh == 0)
                DSTORE(&Af[base0 + rloc + rr], LMU - __log2f(Sc));
        }
        // ---- post fA0; stage B1 of previous iteration ----
        if (it > 0) {
            PW(c0, c1, 64 * it);
            STAGE(sB1, Bf + base1);
        } else {
            PONLY(c0);
        }
        // ---- fA1 ----
        {
            float Sc = sumpass(sx01, sx11, sx21, sy01, sy11, sy21, sB1,
                               rloc, jh, lane, w, pcomb);
            if (lane < 8 && jh == 0)
                DSTORE(&Af[base1 + rloc + rr], LMU - __log2f(Sc));
        }
        PW(c1, c0, 32 * (2 * it + 1));
        STAGE(sA0, Af + base0);
        // ---- gB0 ----
        {
            float Sc = sumpass(sy00, sy10, sy20, sx00, sx10, sx20, sA0,
                               rloc, jh, lane, w, pcomb);
            if (lane < 8 && jh == 0)
                DSTORE(&Bf[base0 + rloc + rr], LMU - __log2f(Sc));
        }
        PW(c0, c1, 32 * (2 * it + 1));
        STAGE(sA1, Af + base1);
        // ---- gB1 ----
        {
            float Sc = sumpass(sy01, sy11, sy21, sx01, sx11, sx21, sA1,
                               rloc, jh, lane, w, pcomb);
            if (lane < 8 && jh == 0)
                DSTORE(&Bf[base1 + rloc + rr], LMU - __log2f(Sc));
        }
        PW(c1, c0, 32 * (2 * it + 2));
        STAGE(sB0, Bf + base0);
    }
    // final B1
    WONLY(c1, 64 * NITERS);
    STAGE(sB1, Bf + base1);

    // ---- epilogue: own 64 rows of each batch, own j-half ----
    {
        float s = epil(sx00, sx10, sx20, sy00, sy10, sy20, sB0, sA0,
                       rloc, jh, lane)
                + epil(sx01, sx11, sx21, sy01, sy11, sy21, sB1, sA1,
                       rloc, jh, lane);
        #pragma unroll
        for (int m = 32; m > 0; m >>= 1) s += __shfl_xor(s, m, 64);
        if (lane == 0) wsum[w] = s;
        __syncthreads();
        if (tid == 0) {
            float t = 0.f;
            #pragma unroll
            for (int i = 0; i < 16; ++i) t += wsum[i];
            atomicAdd(out, t * (1.0f / (float)BB));
        }
    }
    #undef PW
    #undef PONLY
    #undef WONLY
    #undef STAGE
}

extern "C" void kernel_launch(void* const* d_in, const int* in_sizes, int n_in,
                              void* d_out, int out_size, void* d_ws, size_t ws_size,
                              hipStream_t stream) {
    const float* x = (const float*)d_in[0];
    const float* y = (const float*)d_in[1];
    float* out = (float*)d_out;
    char* ws = (char*)d_ws;

    int*   cntb = (int*)ws;                                  // 16 x 256 B
    float* Af   = (float*)(ws + 4096);                       // 128 KB
    float* Bf   = (float*)(ws + 4096 + (size_t)BB*NN*sizeof(float));

    hipMemsetAsync(cntb, 0, 4096, stream);
    hipMemsetAsync(out, 0, sizeof(float), stream);

    const size_t shmem = (size_t)16 * NN * sizeof(float);    // 128 KB
    hipFuncSetAttribute((const void*)emd_sinkhorn,
                        hipFuncAttributeMaxDynamicSharedMemorySize, (int)shmem);

    void* args[] = {(void*)&x, (void*)&y, (void*)&Af, (void*)&Bf,
                    (void*)&cntb, (void*)&out};
    hipError_t e = hipLaunchCooperativeKernel((const void*)emd_sinkhorn,
                                              dim3(256), dim3(1024),
                                              args, shmem, stream);
    if (e != hipSuccess) {
        hipLaunchKernelGGL(emd_sinkhorn, dim3(256), dim3(1024), shmem, stream,
                           x, y, Af, Bf, cntb, out);
    }
}

// Round 12
// 3045.690 us; speedup vs baseline: 1.1179x; 1.1179x over previous
//
#include <hip/hip_runtime.h>

#define BB 16
#define NN 2048
#define NITERS 100

// k = log2(e)/eps, eps = 0.05
#define K2E      28.853900817779268f
#define TWO_K2E  57.707801635558536f
#define INV2K    0.017328679513998632f   // 1/(2k)
#define INV_K2E  0.034657359027997264f
#define INV4K    0.008664339756999316f   // 1/(4k)
#define LMU      (-11.0f)                // log2(1/2048)

#if __has_builtin(__builtin_amdgcn_exp2f)
#define EXP2F(x) __builtin_amdgcn_exp2f(x)
#else
#define EXP2F(x) exp2f(x)
#endif

typedef float v2f __attribute__((ext_vector_type(2)));
typedef unsigned long long u64;

// device-coherent (LLC-homed, sc1) accessors for the dual arrays
#define DSTORE(p, v) __hip_atomic_store((p), (v), __ATOMIC_RELAXED, __HIP_MEMORY_SCOPE_AGENT)

// Sum-pass (R8/R10-verified): 8 rows/wave (coords from LDS, raw = u*INV2K),
// own j-half of SoA tables t0..t2 + dual td. Packed-f32 d-computation.
// Returns combined row-sum on lanes 0..7 (row = rr involution).
__device__ __forceinline__ float sumpass(
    const float* __restrict__ u0, const float* __restrict__ u1,
    const float* __restrict__ u2,
    const float* __restrict__ t0, const float* __restrict__ t1,
    const float* __restrict__ t2, const float* __restrict__ td,
    int rloc, int jh, int lane, int w, float* pcomb)
{
    v2f xp0[4], xp1[4], xp2[4], acc2[4];
    #pragma unroll
    for (int p = 0; p < 4; ++p) {
        xp0[p] = (v2f){u0[rloc + 2*p] * INV2K, u0[rloc + 2*p + 1] * INV2K};
        xp1[p] = (v2f){u1[rloc + 2*p] * INV2K, u1[rloc + 2*p + 1] * INV2K};
        xp2[p] = (v2f){u2[rloc + 2*p] * INV2K, u2[rloc + 2*p + 1] * INV2K};
        acc2[p] = (v2f){0.f, 0.f};
    }
    const int jb = (jh << 10) + lane;
    #pragma unroll 2
    for (int s = 0; s < 16; ++s) {
        const int p = jb + (s << 6);
        const float a0 = t0[p], a1 = t1[p], a2 = t2[p], ad = td[p];
        const v2f a0v = (v2f){a0, a0}, a1v = (v2f){a1, a1};
        const v2f a2v = (v2f){a2, a2}, adv = (v2f){ad, ad};
        #pragma unroll
        for (int q = 0; q < 4; ++q) {
            v2f d = __builtin_elementwise_fma(xp0[q], a0v,
                    __builtin_elementwise_fma(xp1[q], a1v,
                    __builtin_elementwise_fma(xp2[q], a2v, adv)));
            acc2[q] += (v2f){EXP2F(d.x), EXP2F(d.y)};
        }
    }
    float acc[8];
    #pragma unroll
    for (int p = 0; p < 4; ++p) { acc[2*p] = acc2[p].x; acc[2*p+1] = acc2[p].y; }
    // multi-value butterfly (verified R3/R5/R8); lanes<8 end with row rr
    const bool b0 = lane & 1, b1 = lane & 2, b2 = lane & 4;
    float v4[4], v2_[2], v1;
    #pragma unroll
    for (int i = 0; i < 4; ++i) {
        float recv = __shfl_xor(b0 ? acc[i] : acc[i+4], 1, 64);
        v4[i] = (b0 ? acc[i+4] : acc[i]) + recv;
    }
    #pragma unroll
    for (int i = 0; i < 2; ++i) {
        float recv = __shfl_xor(b1 ? v4[i] : v4[i+2], 2, 64);
        v2_[i] = (b1 ? v4[i+2] : v4[i]) + recv;
    }
    {
        float recv = __shfl_xor(b2 ? v2_[0] : v2_[1], 4, 64);
        v1 = (b2 ? v2_[1] : v2_[0]) + recv;
    }
    v1 += __shfl_xor(v1, 8, 64);
    v1 += __shfl_xor(v1, 16, 64);
    v1 += __shfl_xor(v1, 32, 64);
    const int rr = ((lane & 1) << 2) | (lane & 2) | ((lane >> 2) & 1);
    if (lane < 8) pcomb[w * 8 + rr] = v1;
    __syncthreads();
    float S = 0.f;
    if (lane < 8) S = v1 + pcomb[(w ^ 1) * 8 + rr];
    return S;
}

// Epilogue partial (R8-verified): sum_j P_ij*C_ij, 8 rows x own j-half.
__device__ __forceinline__ float epil(
    const float* __restrict__ u0, const float* __restrict__ u1,
    const float* __restrict__ u2,
    const float* __restrict__ t0, const float* __restrict__ t1,
    const float* __restrict__ t2, const float* __restrict__ td,
    const float* __restrict__ sA, int rloc, int jh, int lane)
{
    float xr0[8], xr1[8], xr2[8], Ak[8], x2k[8];
    #pragma unroll
    for (int k = 0; k < 8; ++k) {
        xr0[k] = u0[rloc + k] * INV2K;
        xr1[k] = u1[rloc + k] * INV2K;
        xr2[k] = u2[rloc + k] * INV2K;
        Ak[k]  = sA[rloc + k];
        x2k[k] = K2E * (xr0[k]*xr0[k] + xr1[k]*xr1[k] + xr2[k]*xr2[k]);
    }
    float acc = 0.f;
    const int jb = (jh << 10) + lane;
    for (int s = 0; s < 16; ++s) {
        const int p = jb + (s << 6);
        const float a0 = t0[p], a1 = t1[p], a2 = t2[p], tb = td[p];
        const float q2 = (a0*a0 + a1*a1 + a2*a2) * INV4K;   // k|y|^2
        #pragma unroll
        for (int k = 0; k < 8; ++k) {
            float d = fmaf(xr0[k], a0, fmaf(xr1[k], a1, fmaf(xr2[k], a2, tb)));
            float P = EXP2F(d + Ak[k]);                       // exp(logP)
            float C = fmaxf((x2k[k] + q2 - (d - tb)) * INV_K2E, 0.f);
            acc = fmaf(P, C, acc);
        }
    }
    return acc;
}

// grid: 256 blocks x 1024 threads (1 block/CU). pair = blk&7. Deterministic
// software pipeline (R8-verified schedule). Exchange mechanism rebuilt:
// duals are LLC-homed (sc1); per-batch completion is a 32-slot flag array
// (16 B stride). Post = ONE sc1 release-store of the phase number into own
// slot (no RMW serialization, no wbl2/inv fences — syncthreads' vmcnt(0)
// drains sc1 stores to LLC first). Detect = wave 0 polls all 32 slots in
// parallel (lane i -> slot i, ballot).
__global__ __launch_bounds__(1024) void emd_sinkhorn(
    const float* __restrict__ x, const float* __restrict__ y,
    float* __restrict__ Af, float* __restrict__ Bf,
    int* __restrict__ flags, float* __restrict__ out)
{
    extern __shared__ float S[];     // 16*NN floats = 128 KB
    __shared__ float pcomb[16 * 8];
    __shared__ float wsum[16];

    const int tid  = threadIdx.x;
    const int lane = tid & 63;
    const int w    = tid >> 6;        // 0..15
    const int pr   = w >> 1;          // wave-pair 0..7
    const int jh   = w & 1;           // j-half
    const int blk  = blockIdx.x;
    const int pair = blk & 7;         // = XCD id under round-robin (perf only)
    const int q    = blk >> 3;        // 0..31: row-slice within pair
    const int b0   = pair * 2, b1 = b0 + 1;
    const int base0 = b0 * NN, base1 = b1 * NN;
    const int rloc  = q * 64 + pr * 8;      // within-batch row base
    int* f0 = flags + b0 * 128;       // 32 slots x 16 B per batch
    int* f1 = flags + b1 * 128;

    // LDS carve: per batch 8 slots of NN floats (SoA — conflict-free)
    float *sy00 = S,            *sy10 = S +  1*NN, *sy20 = S +  2*NN;
    float *sx00 = S +  3*NN,    *sx10 = S +  4*NN, *sx20 = S +  5*NN;
    float *sA0  = S +  6*NN,    *sB0  = S +  7*NN;
    float *sy01 = S +  8*NN,    *sy11 = S +  9*NN, *sy21 = S + 10*NN;
    float *sx01 = S + 11*NN,    *sx11 = S + 12*NN, *sx21 = S + 13*NN;
    float *sA1  = S + 14*NN,    *sB1  = S + 15*NN;

    // ---- prologue: stage 2k-scaled tables; B0 = -k|y|^2 ----
    #pragma unroll
    for (int v = 0; v < 2; ++v) {
        const int p = tid + (v << 10);
        {
            const float* px = x + 3 * (size_t)(base0 + p);
            sx00[p] = TWO_K2E * px[0]; sx10[p] = TWO_K2E * px[1]; sx20[p] = TWO_K2E * px[2];
            const float* py = y + 3 * (size_t)(base0 + p);
            const float a = py[0], b = py[1], c = py[2];
            sy00[p] = TWO_K2E * a; sy10[p] = TWO_K2E * b; sy20[p] = TWO_K2E * c;
            sB0[p]  = -K2E * (a*a + b*b + c*c);
        }
        {
            const float* px = x + 3 * (size_t)(base1 + p);
            sx01[p] = TWO_K2E * px[0]; sx11[p] = TWO_K2E * px[1]; sx21[p] = TWO_K2E * px[2];
            const float* py = y + 3 * (size_t)(base1 + p);
            const float a = py[0], b = py[1], c = py[2];
            sy01[p] = TWO_K2E * a; sy11[p] = TWO_K2E * b; sy21[p] = TWO_K2E * c;
            sB1[p]  = -K2E * (a*a + b*b + c*c);
        }
    }
    __syncthreads();

    const int rr = ((lane & 1) << 2) | (lane & 2) | ((lane >> 2) & 1);

    // post own phase number + wait for all 32 slots of the other batch
    #define PW(pslot, pval, warr, tgt) do { __syncthreads();                    \
        if (tid == 0)                                                           \
            __hip_atomic_store((pslot), (pval), __ATOMIC_RELEASE,               \
                               __HIP_MEMORY_SCOPE_AGENT);                       \
        if (w == 0) {                                                           \
            for (;;) {                                                          \
                int vv = (lane < 32)                                            \
                    ? __hip_atomic_load((warr) + lane * 4, __ATOMIC_RELAXED,    \
                                        __HIP_MEMORY_SCOPE_AGENT)               \
                    : 0x7fffffff;                                               \
                if (__ballot(vv >= (tgt)) == ~0ULL) break;                      \
                __builtin_amdgcn_s_sleep(1);                                    \
            }                                                                   \
        }                                                                       \
        __syncthreads(); } while (0)

    #define PONLY(pslot, pval) do { __syncthreads();                            \
        if (tid == 0)                                                           \
            __hip_atomic_store((pslot), (pval), __ATOMIC_RELEASE,               \
                               __HIP_MEMORY_SCOPE_AGENT);                       \
        __syncthreads(); } while (0)

    #define WONLY(warr, tgt) do { __syncthreads();                              \
        if (w == 0) {                                                           \
            for (;;) {                                                          \
                int vv = (lane < 32)                                            \
                    ? __hip_atomic_load((warr) + lane * 4, __ATOMIC_RELAXED,    \
                                        __HIP_MEMORY_SCOPE_AGENT)               \
                    : 0x7fffffff;                                               \
                if (__ballot(vv >= (tgt)) == ~0ULL) break;                      \
                __builtin_amdgcn_s_sleep(1);                                    \
            }                                                                   \
        }                                                                       \
        __syncthreads(); } while (0)

    // stage 2048 duals from LLC into LDS: one 64-bit sc1 load/thread,
    // float2 LDS store (R10-verified conflict-free pattern)
    #define STAGE(dst, src) do {                                                \
        u64 v_ = __hip_atomic_load((const u64*)((src) + 2 * tid),               \
                                   __ATOMIC_RELAXED, __HIP_MEMORY_SCOPE_AGENT); \
        float2 f_; __builtin_memcpy(&f_, &v_, 8);                               \
        ((float2*)(dst))[tid] = f_;                                             \
        __syncthreads(); } while (0)

    for (int it = 0; it < NITERS; ++it) {
        // ---- fA0 ----
        {
            float Sc = sumpass(sx00, sx10, sx20, sy00, sy10, sy20, sB0,
                               rloc, jh, lane, w, pcomb);
            if (lane < 8 && jh == 0)
                DSTORE(&Af[base0 + rloc + rr], LMU - __log2f(Sc));
        }
        // ---- post fA0; stage B1 of previous iteration ----
        if (it > 0) {
            PW(f0 + q * 4, 2 * it + 1, f1, 2 * it);
            STAGE(sB1, Bf + base1);
        } else {
            PONLY(f0 + q * 4, 1);
        }
        // ---- fA1 ----
        {
            float Sc = sumpass(sx01, sx11, sx21, sy01, sy11, sy21, sB1,
                               rloc, jh, lane, w, pcomb);
            if (lane < 8 && jh == 0)
                DSTORE(&Af[base1 + rloc + rr], LMU - __log2f(Sc));
        }
        PW(f1 + q * 4, 2 * it + 1, f0, 2 * it + 1);
        STAGE(sA0, Af + base0);
        // ---- gB0 ----
        {
            float Sc = sumpass(sy00, sy10, sy20, sx00, sx10, sx20, sA0,
                               rloc, jh, lane, w, pcomb);
            if (lane < 8 && jh == 0)
                DSTORE(&Bf[base0 + rloc + rr], LMU - __log2f(Sc));
        }
        PW(f0 + q * 4, 2 * it + 2, f1, 2 * it + 1);
        STAGE(sA1, Af + base1);
        // ---- gB1 ----
        {
            float Sc = sumpass(sy01, sy11, sy21, sx01, sx11, sx21, sA1,
                               rloc, jh, lane, w, pcomb);
            if (lane < 8 && jh == 0)
                DSTORE(&Bf[base1 + rloc + rr], LMU - __log2f(Sc));
        }
        PW(f1 + q * 4, 2 * it + 2, f0, 2 * it + 2);
        STAGE(sB0, Bf + base0);
    }
    // final B1
    WONLY(f1, 2 * NITERS);
    STAGE(sB1, Bf + base1);

    // ---- epilogue: own 64 rows of each batch, own j-half ----
    {
        float s = epil(sx00, sx10, sx20, sy00, sy10, sy20, sB0, sA0,
                       rloc, jh, lane)
                + epil(sx01, sx11, sx21, sy01, sy11, sy21, sB1, sA1,
                       rloc, jh, lane);
        #pragma unroll
        for (int m = 32; m > 0; m >>= 1) s += __shfl_xor(s, m, 64);
        if (lane == 0) wsum[w] = s;
        __syncthreads();
        if (tid == 0) {
            float t = 0.f;
            #pragma unroll
            for (int i = 0; i < 16; ++i) t += wsum[i];
            atomicAdd(out, t * (1.0f / (float)BB));
        }
    }
    #undef PW
    #undef PONLY
    #undef WONLY
    #undef STAGE
}

extern "C" void kernel_launch(void* const* d_in, const int* in_sizes, int n_in,
                              void* d_out, int out_size, void* d_ws, size_t ws_size,
                              hipStream_t stream) {
    const float* x = (const float*)d_in[0];
    const float* y = (const float*)d_in[1];
    float* out = (float*)d_out;
    char* ws = (char*)d_ws;

    int*   flags = (int*)ws;                                 // 16 x 32 x 16 B = 8 KB
    float* Af    = (float*)(ws + 8192);                      // 128 KB
    float* Bf    = (float*)(ws + 8192 + (size_t)BB*NN*sizeof(float));

    hipMemsetAsync(flags, 0, 8192, stream);
    hipMemsetAsync(out, 0, sizeof(float), stream);

    const size_t shmem = (size_t)16 * NN * sizeof(float);    // 128 KB
    hipFuncSetAttribute((const void*)emd_sinkhorn,
                        hipFuncAttributeMaxDynamicSharedMemorySize, (int)shmem);

    void* args[] = {(void*)&x, (void*)&y, (void*)&Af, (void*)&Bf,
                    (void*)&flags, (void*)&out};
    hipError_t e = hipLaunchCooperativeKernel((const void*)emd_sinkhorn,
                                              dim3(256), dim3(1024),
                                              args, shmem, stream);
    if (e != hipSuccess) {
        hipLaunchKernelGGL(emd_sinkhorn, dim3(256), dim3(1024), shmem, stream,
                           x, y, Af, Bf, flags, out);
    }
}

// Round 13
// 2935.768 us; speedup vs baseline: 1.1597x; 1.0374x over previous
//
#include <hip/hip_runtime.h>

#define BB 16
#define NN 2048
#define NITERS 100

// k = log2(e)/eps, eps = 0.05
#define K2E      28.853900817779268f
#define TWO_K2E  57.707801635558536f
#define INV2K    0.017328679513998632f   // 1/(2k)
#define INV_K2E  0.034657359027997264f
#define INV4K    0.008664339756999316f   // 1/(4k)
#define LMU      (-11.0f)                // log2(1/2048)

#if __has_builtin(__builtin_amdgcn_exp2f)
#define EXP2F(x) __builtin_amdgcn_exp2f(x)
#else
#define EXP2F(x) exp2f(x)
#endif

typedef float v2f __attribute__((ext_vector_type(2)));

// device-coherent (LLC-homed, sc1) accessors for the dual arrays
#define DSTORE(p, v) __hip_atomic_store((p), (v), __ATOMIC_RELAXED, __HIP_MEMORY_SCOPE_AGENT)
#define DLOAD(p)     __hip_atomic_load((p), __ATOMIC_RELAXED, __HIP_MEMORY_SCOPE_AGENT)

// Sum-pass: 8 rows/wave (coords from LDS, raw = u*INV2K), own j-half of LDS
// SoA tables t0..t2; dual read DIRECTLY from LLC (sc1), 16 preloaded values
// consumed across the pass (latency hidden under compute + 16-wave TLP).
// Packed-f32 d-computation. Returns combined row-sum on lanes 0..7.
__device__ __forceinline__ float sumpassG(
    const float* __restrict__ u0, const float* __restrict__ u1,
    const float* __restrict__ u2,
    const float* __restrict__ t0, const float* __restrict__ t1,
    const float* __restrict__ t2, const float* __restrict__ gd,
    int rloc, int jh, int lane, int w, float* pcomb)
{
    const int jb = (jh << 10) + lane;
    float dv[16];
    #pragma unroll
    for (int s = 0; s < 16; ++s)
        dv[s] = DLOAD(gd + jb + (s << 6));

    v2f xp0[4], xp1[4], xp2[4], acc2[4];
    #pragma unroll
    for (int p = 0; p < 4; ++p) {
        xp0[p] = (v2f){u0[rloc + 2*p] * INV2K, u0[rloc + 2*p + 1] * INV2K};
        xp1[p] = (v2f){u1[rloc + 2*p] * INV2K, u1[rloc + 2*p + 1] * INV2K};
        xp2[p] = (v2f){u2[rloc + 2*p] * INV2K, u2[rloc + 2*p + 1] * INV2K};
        acc2[p] = (v2f){0.f, 0.f};
    }
    #pragma unroll 2
    for (int s = 0; s < 16; ++s) {
        const int p = jb + (s << 6);
        const float a0 = t0[p], a1 = t1[p], a2 = t2[p], ad = dv[s];
        const v2f a0v = (v2f){a0, a0}, a1v = (v2f){a1, a1};
        const v2f a2v = (v2f){a2, a2}, adv = (v2f){ad, ad};
        #pragma unroll
        for (int q = 0; q < 4; ++q) {
            v2f d = __builtin_elementwise_fma(xp0[q], a0v,
                    __builtin_elementwise_fma(xp1[q], a1v,
                    __builtin_elementwise_fma(xp2[q], a2v, adv)));
            acc2[q] += (v2f){EXP2F(d.x), EXP2F(d.y)};
        }
    }
    float acc[8];
    #pragma unroll
    for (int p = 0; p < 4; ++p) { acc[2*p] = acc2[p].x; acc[2*p+1] = acc2[p].y; }
    // multi-value butterfly (verified R3/R5/R8); lanes<8 end with row rr
    const bool b0 = lane & 1, b1 = lane & 2, b2 = lane & 4;
    float v4[4], v2_[2], v1;
    #pragma unroll
    for (int i = 0; i < 4; ++i) {
        float recv = __shfl_xor(b0 ? acc[i] : acc[i+4], 1, 64);
        v4[i] = (b0 ? acc[i+4] : acc[i]) + recv;
    }
    #pragma unroll
    for (int i = 0; i < 2; ++i) {
        float recv = __shfl_xor(b1 ? v4[i] : v4[i+2], 2, 64);
        v2_[i] = (b1 ? v4[i+2] : v4[i]) + recv;
    }
    {
        float recv = __shfl_xor(b2 ? v2_[0] : v2_[1], 4, 64);
        v1 = (b2 ? v2_[1] : v2_[0]) + recv;
    }
    v1 += __shfl_xor(v1, 8, 64);
    v1 += __shfl_xor(v1, 16, 64);
    v1 += __shfl_xor(v1, 32, 64);
    const int rr = ((lane & 1) << 2) | (lane & 2) | ((lane >> 2) & 1);
    if (lane < 8) pcomb[w * 8 + rr] = v1;
    __syncthreads();
    float S = 0.f;
    if (lane < 8) S = v1 + pcomb[(w ^ 1) * 8 + rr];
    return S;
}

// Epilogue partial: sum_j P_ij*C_ij, 8 rows x own j-half. B from LLC (sc1
// preload), A from Aval (last f-pass Sc, lanes 0..7) via involution shuffle.
__device__ __forceinline__ float epilG(
    const float* __restrict__ u0, const float* __restrict__ u1,
    const float* __restrict__ u2,
    const float* __restrict__ t0, const float* __restrict__ t1,
    const float* __restrict__ t2, const float* __restrict__ gB,
    float Aval, int rloc, int jh, int lane)
{
    const int jb = (jh << 10) + lane;
    float dv[16];
    #pragma unroll
    for (int s = 0; s < 16; ++s)
        dv[s] = DLOAD(gB + jb + (s << 6));

    float xr0[8], xr1[8], xr2[8], Ak[8], x2k[8];
    #pragma unroll
    for (int k = 0; k < 8; ++k) {
        xr0[k] = u0[rloc + k] * INV2K;
        xr1[k] = u1[rloc + k] * INV2K;
        xr2[k] = u2[rloc + k] * INV2K;
        const int src = ((k & 1) << 2) | (k & 2) | ((k >> 2) & 1);
        Ak[k]  = __shfl(Aval, src, 64);
        x2k[k] = K2E * (xr0[k]*xr0[k] + xr1[k]*xr1[k] + xr2[k]*xr2[k]);
    }
    float acc = 0.f;
    for (int s = 0; s < 16; ++s) {
        const int p = jb + (s << 6);
        const float a0 = t0[p], a1 = t1[p], a2 = t2[p], tb = dv[s];
        const float q2 = (a0*a0 + a1*a1 + a2*a2) * INV4K;   // k|y|^2
        #pragma unroll
        for (int k = 0; k < 8; ++k) {
            float d = fmaf(xr0[k], a0, fmaf(xr1[k], a1, fmaf(xr2[k], a2, tb)));
            float P = EXP2F(d + Ak[k]);                       // exp(logP)
            float C = fmaxf((x2k[k] + q2 - (d - tb)) * INV_K2E, 0.f);
            acc = fmaf(P, C, acc);
        }
    }
    return acc;
}

// grid: 256 blocks x 1024 threads (1 block/CU). pair = blk&7. Deterministic
// software pipeline (R8/R12-verified): every wait has one full compute phase
// between the matching posts and the wait. Duals are LLC-homed (sc1) and
// consumed directly from LLC inside the compute loop — no LDS staging
// section. Flag array (32 slots x 16 B per batch): post = one sc1 release
// store; detect = wave 0 parallel poll + ballot (R12-verified).
__global__ __launch_bounds__(1024) void emd_sinkhorn(
    const float* __restrict__ x, const float* __restrict__ y,
    float* __restrict__ Af, float* __restrict__ Bf,
    int* __restrict__ flags, float* __restrict__ out)
{
    extern __shared__ float S[];     // 12*NN floats = 96 KB
    __shared__ float pcomb[16 * 8];
    __shared__ float wsum[16];

    const int tid  = threadIdx.x;
    const int lane = tid & 63;
    const int w    = tid >> 6;        // 0..15
    const int pr   = w >> 1;          // wave-pair 0..7
    const int jh   = w & 1;           // j-half
    const int blk  = blockIdx.x;
    const int pair = blk & 7;         // = XCD id under round-robin (perf only)
    const int q    = blk >> 3;        // 0..31: row-slice within pair
    const int b0   = pair * 2, b1 = b0 + 1;
    const int base0 = b0 * NN, base1 = b1 * NN;
    const int rloc  = q * 64 + pr * 8;      // within-batch row base
    int* f0 = flags + b0 * 128;       // 32 slots x 16 B per batch
    int* f1 = flags + b1 * 128;

    // LDS carve: per batch 6 table slots of NN floats (SoA — conflict-free)
    float *sy00 = S,            *sy10 = S +  1*NN, *sy20 = S +  2*NN;
    float *sx00 = S +  3*NN,    *sx10 = S +  4*NN, *sx20 = S +  5*NN;
    float *sy01 = S +  6*NN,    *sy11 = S +  7*NN, *sy21 = S +  8*NN;
    float *sx01 = S +  9*NN,    *sx11 = S + 10*NN, *sx21 = S + 11*NN;

    // ---- prologue: stage 2k-scaled tables ----
    #pragma unroll
    for (int v = 0; v < 2; ++v) {
        const int p = tid + (v << 10);
        {
            const float* px = x + 3 * (size_t)(base0 + p);
            sx00[p] = TWO_K2E * px[0]; sx10[p] = TWO_K2E * px[1]; sx20[p] = TWO_K2E * px[2];
            const float* py = y + 3 * (size_t)(base0 + p);
            sy00[p] = TWO_K2E * py[0]; sy10[p] = TWO_K2E * py[1]; sy20[p] = TWO_K2E * py[2];
        }
        {
            const float* px = x + 3 * (size_t)(base1 + p);
            sx01[p] = TWO_K2E * px[0]; sx11[p] = TWO_K2E * px[1]; sx21[p] = TWO_K2E * px[2];
            const float* py = y + 3 * (size_t)(base1 + p);
            sy01[p] = TWO_K2E * py[0]; sy11[p] = TWO_K2E * py[1]; sy21[p] = TWO_K2E * py[2];
        }
    }
    // ---- prologue: B0-init for own 64 columns of both batches (sc1) ----
    if (tid < 128) {
        const int bb  = tid >> 6;
        const int col = q * 64 + (tid & 63);
        const int bs  = bb ? base1 : base0;
        const float* py = y + 3 * (size_t)(bs + col);
        const float a = py[0], b = py[1], c = py[2];
        DSTORE(&Bf[bs + col], -K2E * (a*a + b*b + c*c));
    }
    __syncthreads();                  // drains table + B-init stores
    if (tid == 0) {
        __hip_atomic_store(f0 + q * 4, 1, __ATOMIC_RELEASE, __HIP_MEMORY_SCOPE_AGENT);
        __hip_atomic_store(f1 + q * 4, 1, __ATOMIC_RELEASE, __HIP_MEMORY_SCOPE_AGENT);
    }

    const int rr = ((lane & 1) << 2) | (lane & 2) | ((lane >> 2) & 1);

    // post own phase into own slot + wait all 32 slots of the other array
    #define PW(pslot, pval, warr, tgt) do { __syncthreads();                    \
        if (tid == 0)                                                           \
            __hip_atomic_store((pslot), (pval), __ATOMIC_RELEASE,               \
                               __HIP_MEMORY_SCOPE_AGENT);                       \
        if (w == 0) {                                                           \
            for (;;) {                                                          \
                int vv = (lane < 32)                                            \
                    ? __hip_atomic_load((warr) + lane * 4, __ATOMIC_RELAXED,    \
                                        __HIP_MEMORY_SCOPE_AGENT)               \
                    : 0x7fffffff;                                               \
                if (__ballot(vv >= (tgt)) == ~0ULL) break;                      \
                __builtin_amdgcn_s_sleep(1);                                    \
            }                                                                   \
        }                                                                       \
        __syncthreads(); } while (0)

    #define WONLY(warr, tgt) do { __syncthreads();                              \
        if (w == 0) {                                                           \
            for (;;) {                                                          \
                int vv = (lane < 32)                                            \
                    ? __hip_atomic_load((warr) + lane * 4, __ATOMIC_RELAXED,    \
                                        __HIP_MEMORY_SCOPE_AGENT)               \
                    : 0x7fffffff;                                               \
                if (__ballot(vv >= (tgt)) == ~0ULL) break;                      \
                __builtin_amdgcn_s_sleep(1);                                    \
            }                                                                   \
        }                                                                       \
        __syncthreads(); } while (0)

    WONLY(f0, 1);                     // initial B0 ready (one-time, low slack)

    float Aval0 = 0.f, Aval1 = 0.f;

    for (int it = 0; it < NITERS; ++it) {
        // ---- fA0: dual = Bf[batch0] (ready: waited 2it+1 at loop bottom) ----
        {
            float Sc = sumpassG(sx00, sx10, sx20, sy00, sy10, sy20, Bf + base0,
                                rloc, jh, lane, w, pcomb);
            Aval0 = LMU - __log2f(Sc);
            if (lane < 8 && jh == 0) DSTORE(&Af[base0 + rloc + rr], Aval0);
        }
        PW(f0 + q * 4, 2 * it + 2, f1, 2 * it + 1);   // post A0; wait B1
        // ---- fA1 ----
        {
            float Sc = sumpassG(sx01, sx11, sx21, sy01, sy11, sy21, Bf + base1,
                                rloc, jh, lane, w, pcomb);
            Aval1 = LMU - __log2f(Sc);
            if (lane < 8 && jh == 0) DSTORE(&Af[base1 + rloc + rr], Aval1);
        }
        PW(f1 + q * 4, 2 * it + 2, f0, 2 * it + 2);   // post A1; wait A0
        // ---- gB0: dual = Af[batch0] ----
        {
            float Sc = sumpassG(sy00, sy10, sy20, sx00, sx10, sx20, Af + base0,
                                rloc, jh, lane, w, pcomb);
            if (lane < 8 && jh == 0)
                DSTORE(&Bf[base0 + rloc + rr], LMU - __log2f(Sc));
        }
        PW(f0 + q * 4, 2 * it + 3, f1, 2 * it + 2);   // post B0; wait A1
        // ---- gB1 ----
        {
            float Sc = sumpassG(sy01, sy11, sy21, sx01, sx11, sx21, Af + base1,
                                rloc, jh, lane, w, pcomb);
            if (lane < 8 && jh == 0)
                DSTORE(&Bf[base1 + rloc + rr], LMU - __log2f(Sc));
        }
        PW(f1 + q * 4, 2 * it + 3, f0, 2 * it + 3);   // post B1; wait B0-new
    }
    // epilogue needs final B1 too
    WONLY(f1, 2 * NITERS + 1);

    // ---- epilogue: own 64 rows of each batch, own j-half ----
    {
        float s = epilG(sx00, sx10, sx20, sy00, sy10, sy20, Bf + base0,
                        Aval0, rloc, jh, lane)
                + epilG(sx01, sx11, sx21, sy01, sy11, sy21, Bf + base1,
                        Aval1, rloc, jh, lane);
        #pragma unroll
        for (int m = 32; m > 0; m >>= 1) s += __shfl_xor(s, m, 64);
        if (lane == 0) wsum[w] = s;
        __syncthreads();
        if (tid == 0) {
            float t = 0.f;
            #pragma unroll
            for (int i = 0; i < 16; ++i) t += wsum[i];
            atomicAdd(out, t * (1.0f / (float)BB));
        }
    }
    #undef PW
    #undef WONLY
}

extern "C" void kernel_launch(void* const* d_in, const int* in_sizes, int n_in,
                              void* d_out, int out_size, void* d_ws, size_t ws_size,
                              hipStream_t stream) {
    const float* x = (const float*)d_in[0];
    const float* y = (const float*)d_in[1];
    float* out = (float*)d_out;
    char* ws = (char*)d_ws;

    int*   flags = (int*)ws;                                 // 16 x 32 x 16 B = 8 KB
    float* Af    = (float*)(ws + 8192);                      // 128 KB
    float* Bf    = (float*)(ws + 8192 + (size_t)BB*NN*sizeof(float));

    hipMemsetAsync(flags, 0, 8192, stream);
    hipMemsetAsync(out, 0, sizeof(float), stream);

    const size_t shmem = (size_t)12 * NN * sizeof(float);    // 96 KB
    hipFuncSetAttribute((const void*)emd_sinkhorn,
                        hipFuncAttributeMaxDynamicSharedMemorySize, (int)shmem);

    void* args[] = {(void*)&x, (void*)&y, (void*)&Af, (void*)&Bf,
                    (void*)&flags, (void*)&out};
    hipError_t e = hipLaunchCooperativeKernel((const void*)emd_sinkhorn,
                                              dim3(256), dim3(1024),
                                              args, shmem, stream);
    if (e != hipSuccess) {
        hipLaunchKernelGGL(emd_sinkhorn, dim3(256), dim3(1024), shmem, stream,
                           x, y, Af, Bf, flags, out);
    }
}